// Round 1
// baseline (586.264 us; speedup 1.0000x reference)
//
#include <hip/hip_runtime.h>
#include <hip/hip_bf16.h>

// BanditLayer inference: out[M,N] = x[M,K] . w[N,K]^T + bias[N], fp32 I/O.
// Strategy: fp32->bf16 pre-pass into d_ws, then m97-structure bf16 MFMA GEMM
// (128x128 tile, BK=32, global_load_lds width=16, XCD swizzle, fused bias).

typedef __bf16 bf16x8 __attribute__((ext_vector_type(8)));
typedef float f32x4 __attribute__((ext_vector_type(4)));

#define GM 4096
#define GK 4096
#define GN 8192
#define BM 128
#define BN 128
#define BK 32

__device__ __forceinline__ unsigned short f2bf_rne(float f) {
  union { float f; unsigned u; } v; v.f = f;
  unsigned r = 0x7FFFu + ((v.u >> 16) & 1u);
  return (unsigned short)((v.u + r) >> 16);
}

__global__ void cvt_f32_to_bf16(const float* __restrict__ in,
                                unsigned short* __restrict__ out, int n4) {
  int i = blockIdx.x * blockDim.x + threadIdx.x;
  int stride = gridDim.x * blockDim.x;
  const float4* in4 = reinterpret_cast<const float4*>(in);
  ushort4* out4 = reinterpret_cast<ushort4*>(out);
  for (; i < n4; i += stride) {
    float4 v = in4[i];
    ushort4 o;
    o.x = f2bf_rne(v.x);
    o.y = f2bf_rne(v.y);
    o.z = f2bf_rne(v.z);
    o.w = f2bf_rne(v.w);
    out4[i] = o;
  }
}

__device__ __forceinline__ void gload_lds16(const void* g, void* l) {
  __builtin_amdgcn_global_load_lds(
      (const __attribute__((address_space(1))) unsigned int*)g,
      (__attribute__((address_space(3))) unsigned int*)l, 16, 0, 0);
}

__launch_bounds__(256)
__global__ void gemm_bt_bias(const unsigned short* __restrict__ A,  // GM x GK bf16
                             const unsigned short* __restrict__ B,  // GN x GK bf16
                             const float* __restrict__ bias,
                             float* __restrict__ C) {
  __shared__ __align__(16) unsigned short As[BM * BK];  // 8 KB
  __shared__ __align__(16) unsigned short Bs[BN * BK];  // 8 KB

  // XCD-aware bijective swizzle: nwg = 2048, divisible by 8.
  const int nwg = (GM / BM) * (GN / BN);   // 2048
  int bid = blockIdx.x;
  int swz = (bid & 7) * (nwg >> 3) + (bid >> 3);
  const int TILES_M = GM / BM;             // 32
  int bm = swz % TILES_M;
  int bn = swz / TILES_M;

  const int tid  = threadIdx.x;
  const int lane = tid & 63;
  const int wave = tid >> 6;
  const int wm = wave >> 1;   // 0..1
  const int wn = wave & 1;    // 0..1

  // Staging: 16B chunks, row = c>>2, col = (c&3)*8 within a [128][32] bf16 tile.
  // LDS element offset of chunk c is exactly c*8 -> linear lane order matches
  // global_load_lds's (wave-uniform base + lane*16) destination rule.
  const int c0 = tid, c1 = tid + 256;
  const unsigned short* ag0 = A + (size_t)(bm * BM + (c0 >> 2)) * GK + (c0 & 3) * 8;
  const unsigned short* ag1 = A + (size_t)(bm * BM + (c1 >> 2)) * GK + (c1 & 3) * 8;
  const unsigned short* bg0 = B + (size_t)(bn * BN + (c0 >> 2)) * GK + (c0 & 3) * 8;
  const unsigned short* bg1 = B + (size_t)(bn * BN + (c1 >> 2)) * GK + (c1 & 3) * 8;
  unsigned short* al0 = &As[(wave * 64) * 8];
  unsigned short* al1 = &As[(256 + wave * 64) * 8];
  unsigned short* bl0 = &Bs[(wave * 64) * 8];
  unsigned short* bl1 = &Bs[(256 + wave * 64) * 8];

  f32x4 acc[4][4];
  #pragma unroll
  for (int i = 0; i < 4; ++i)
    #pragma unroll
    for (int j = 0; j < 4; ++j)
      acc[i][j] = (f32x4){0.f, 0.f, 0.f, 0.f};

  const int frow = lane & 15;
  const int fk   = (lane >> 4) * 8;

  for (int k0 = 0; k0 < GK; k0 += BK) {
    gload_lds16(ag0 + k0, al0);
    gload_lds16(ag1 + k0, al1);
    gload_lds16(bg0 + k0, bl0);
    gload_lds16(bg1 + k0, bl1);
    __syncthreads();  // compiler drains vmcnt(0) before s_barrier -> LDS ready

    bf16x8 af[4], bf[4];
    #pragma unroll
    for (int i = 0; i < 4; ++i)
      af[i] = *reinterpret_cast<const bf16x8*>(&As[(wm * 64 + i * 16 + frow) * BK + fk]);
    #pragma unroll
    for (int j = 0; j < 4; ++j)
      bf[j] = *reinterpret_cast<const bf16x8*>(&Bs[(wn * 64 + j * 16 + frow) * BK + fk]);

    #pragma unroll
    for (int i = 0; i < 4; ++i)
      #pragma unroll
      for (int j = 0; j < 4; ++j)
        acc[i][j] = __builtin_amdgcn_mfma_f32_16x16x32_bf16(af[i], bf[j], acc[i][j], 0, 0, 0);

    __syncthreads();  // all waves done reading before next stage overwrites
  }

  // Epilogue: C/D layout col = lane&15, row = (lane>>4)*4 + r  (m89-verified).
  float bv[4];
  #pragma unroll
  for (int j = 0; j < 4; ++j)
    bv[j] = bias[bn * BN + wn * 64 + j * 16 + frow];
  const int rbase = (lane >> 4) * 4;
  #pragma unroll
  for (int i = 0; i < 4; ++i) {
    #pragma unroll
    for (int r = 0; r < 4; ++r) {
      int m = bm * BM + wm * 64 + i * 16 + rbase + r;
      float* crow = C + (size_t)m * GN + bn * BN + wn * 64 + frow;
      #pragma unroll
      for (int j = 0; j < 4; ++j)
        crow[j * 16] = acc[i][j][r] + bv[j];
    }
  }
}

extern "C" void kernel_launch(void* const* d_in, const int* in_sizes, int n_in,
                              void* d_out, int out_size, void* d_ws, size_t ws_size,
                              hipStream_t stream) {
  const float* x    = (const float*)d_in[0];
  const float* w    = (const float*)d_in[1];
  const float* bias = (const float*)d_in[2];
  float* out = (float*)d_out;

  // Workspace layout: [x_bf16: GM*GK][w_bf16: GN*GK]  = 100.7 MB total
  unsigned short* xbf = (unsigned short*)d_ws;
  unsigned short* wbf = xbf + (size_t)GM * GK;

  const int n4x = (GM * GK) / 4;
  const int n4w = (GN * GK) / 4;
  cvt_f32_to_bf16<<<2048, 256, 0, stream>>>(x, xbf, n4x);
  cvt_f32_to_bf16<<<2048, 256, 0, stream>>>(w, wbf, n4w);

  const int nwg = (GM / BM) * (GN / BN);  // 2048
  gemm_bt_bias<<<nwg, 256, 0, stream>>>(xbf, wbf, bias, out);
}

// Round 3
// 545.119 us; speedup vs baseline: 1.0755x; 1.0755x over previous
//
#include <hip/hip_runtime.h>
#include <hip/hip_bf16.h>

// BanditLayer inference: out[M,N] = x[M,K] . w[N,K]^T + bias[N], fp32 I/O.
// Round 3: 256x256 bf16 MFMA GEMM, BK=32, 3-deep LDS pipeline (96KB),
// counted vmcnt(4) (never drain in main loop), XOR-swizzled LDS reads via
// pre-swizzled global_load_lds sources, setprio around 16-MFMA clusters,
// XCD-bijective block swizzle, fused bias. Plus single fused fp32->bf16 cvt.

typedef __bf16 bf16x8 __attribute__((ext_vector_type(8)));
typedef float f32x4 __attribute__((ext_vector_type(4)));

#define GM 4096
#define GK 4096
#define GN 8192
#define BM 256
#define BN 256
#define BK 32
#define NT (GK / BK)   // 128 K-tiles

__device__ __forceinline__ unsigned f2bf_rne(float f) {
  union { float f; unsigned u; } v; v.f = f;
  unsigned r = 0x7FFFu + ((v.u >> 16) & 1u);
  return (v.u + r) >> 16;
}

// One launch converts both x and w: fp32 -> packed bf16, 8 elems/thread/iter.
__global__ void cvt_both(const float4* __restrict__ x4, const float4* __restrict__ w4,
                         uint4* __restrict__ xo4, uint4* __restrict__ wo4,
                         int n8x, int n8t) {
  int i = blockIdx.x * blockDim.x + threadIdx.x;
  int stride = gridDim.x * blockDim.x;
  for (; i < n8t; i += stride) {
    const float4* s; uint4* d; int j;
    if (i < n8x) { s = x4; d = xo4; j = i; }
    else         { s = w4; d = wo4; j = i - n8x; }
    float4 a = s[2 * j];
    float4 b = s[2 * j + 1];
    uint4 o;
    o.x = f2bf_rne(a.x) | (f2bf_rne(a.y) << 16);
    o.y = f2bf_rne(a.z) | (f2bf_rne(a.w) << 16);
    o.z = f2bf_rne(b.x) | (f2bf_rne(b.y) << 16);
    o.w = f2bf_rne(b.z) | (f2bf_rne(b.w) << 16);
    d[j] = o;
  }
}

__device__ __forceinline__ void gload_lds16(const void* g, void* l) {
  __builtin_amdgcn_global_load_lds(
      (const __attribute__((address_space(1))) unsigned int*)g,
      (__attribute__((address_space(3))) unsigned int*)l, 16, 0, 0);
}

// LDS tile: [256 rows][32 k] bf16 = 16KB/operand/buffer; rows are 64B = 4
// slots of 16B. Swizzle: phys_slot = logical_slot ^ (row & 3). Staging writes
// the PHYSICAL layout linearly (global_load_lds dest = uniform base+lane*16),
// so the global SOURCE column is pre-swizzled (rule 21/m173); ds_read applies
// the same XOR. 64-lane b128 fragment reads are then exactly conflict-free.

__launch_bounds__(512, 2)
__global__ void gemm_bt_bias(const unsigned short* __restrict__ A,  // GM x GK bf16
                             const unsigned short* __restrict__ B,  // GN x GK bf16
                             const float* __restrict__ bias,
                             float* __restrict__ C) {
  __shared__ __align__(1024) unsigned short As[3][BM * BK];  // 48 KB
  __shared__ __align__(1024) unsigned short Bs[3][BN * BK];  // 48 KB

  // XCD-aware bijective swizzle (512 wgs, %8==0).
  const int nwg = (GM / BM) * (GN / BN);   // 512
  int bid = blockIdx.x;
  int swz = (bid & 7) * (nwg >> 3) + (bid >> 3);
  const int bm = swz & 15;    // 16 tiles along M
  const int bn = swz >> 4;    // 32 tiles along N

  const int tid  = threadIdx.x;   // 0..511
  const int lane = tid & 63;
  const int wave = tid >> 6;      // 0..7
  const int wm = wave >> 2;       // 0..1  (M half: 128 rows)
  const int wn = wave & 3;        // 0..3  (N quarter: 64 cols)
  const int lr = lane & 15;
  const int lg = lane >> 4;       // 0..3

  // ---- staging: 1024 chunks of 16B per operand tile; thread covers c0=tid,
  // c1=tid+512. Pre-swizzled global source column. ----
  const int c0 = tid,       r0 = c0 >> 2, s0 = (c0 & 3) ^ (r0 & 3);
  const int c1 = tid + 512, r1 = c1 >> 2, s1 = (c1 & 3) ^ (r1 & 3);
  const unsigned short* aG0 = A + (size_t)(bm * BM + r0) * GK + s0 * 8;
  const unsigned short* aG1 = A + (size_t)(bm * BM + r1) * GK + s1 * 8;
  const unsigned short* bG0 = B + (size_t)(bn * BN + r0) * GK + s0 * 8;
  const unsigned short* bG1 = B + (size_t)(bn * BN + r1) * GK + s1 * 8;
  // LDS dest element offsets (wave-uniform base; HW adds lane*16B).
  const int d0 = (wave * 64) * 8;
  const int d1 = (512 + wave * 64) * 8;

#define STAGE_A(buf, kt) do { \
    gload_lds16(aG0 + (size_t)(kt) * BK, &As[buf][d0]); \
    gload_lds16(aG1 + (size_t)(kt) * BK, &As[buf][d1]); \
  } while (0)
#define STAGE_B(buf, kt) do { \
    gload_lds16(bG0 + (size_t)(kt) * BK, &Bs[buf][d0]); \
    gload_lds16(bG1 + (size_t)(kt) * BK, &Bs[buf][d1]); \
  } while (0)

  // ---- fragment read byte-offsets within one buffer ----
  // A frag i: row = wm*128 + i*16 + lr, slot = lg, phys = lg ^ (lr&3)
  // (row&3 == lr&3 since row-base is a multiple of 16). Row stride 64B.
  const int phys = lg ^ (lr & 3);
  const int aOff = (wm * 128 + lr) * 64 + phys * 16;   // + i*1024
  const int bOff = (wn * 64 + lr) * 64 + phys * 16;    // + j*1024

  f32x4 acc[8][4];
  #pragma unroll
  for (int i = 0; i < 8; ++i)
    #pragma unroll
    for (int j = 0; j < 4; ++j)
      acc[i][j] = (f32x4){0.f, 0.f, 0.f, 0.f};

  // ---- prologue: stage tiles 0 (buf0) and 1 (buf1) ----
  STAGE_A(0, 0); STAGE_B(0, 0);
  STAGE_A(1, 1); STAGE_B(1, 1);
  asm volatile("s_waitcnt vmcnt(4)" ::: "memory");   // tile 0 landed
  __builtin_amdgcn_s_barrier();

  int b = 0;
  for (int t = 0; t < NT; ++t) {
    const bool st = (t + 2) < NT;
    const int s = (b == 0) ? 2 : (b - 1);            // (b+2)%3: buffer for t+2
    const char* aB = (const char*)&As[b][0];
    const char* bB = (const char*)&Bs[b][0];

    bf16x8 af[8], bf[4];

    // ---- P1: read af[0..3], bf[0..3]; stage A(t+2); MFMA (m0-3 x n0-3) ----
    #pragma unroll
    for (int i = 0; i < 4; ++i)
      af[i] = *(const bf16x8*)(aB + aOff + i * 1024);
    #pragma unroll
    for (int j = 0; j < 4; ++j)
      bf[j] = *(const bf16x8*)(bB + bOff + j * 1024);
    if (st) STAGE_A(s, t + 2);
    __builtin_amdgcn_s_barrier();
    asm volatile("s_waitcnt lgkmcnt(0)" ::: "memory");
    __builtin_amdgcn_s_setprio(1);
    #pragma unroll
    for (int i = 0; i < 4; ++i)
      #pragma unroll
      for (int j = 0; j < 4; ++j)
        acc[i][j] = __builtin_amdgcn_mfma_f32_16x16x32_bf16(af[i], bf[j], acc[i][j], 0, 0, 0);
    __builtin_amdgcn_s_setprio(0);
    __builtin_amdgcn_s_barrier();

    // ---- P2: read af[4..7]; stage B(t+2); MFMA (m4-7 x n0-3); counted vmcnt ----
    #pragma unroll
    for (int i = 0; i < 4; ++i)
      af[4 + i] = *(const bf16x8*)(aB + aOff + (4 + i) * 1024);
    if (st) STAGE_B(s, t + 2);
    __builtin_amdgcn_s_barrier();
    asm volatile("s_waitcnt lgkmcnt(0)" ::: "memory");
    __builtin_amdgcn_s_setprio(1);
    #pragma unroll
    for (int i = 0; i < 4; ++i)
      #pragma unroll
      for (int j = 0; j < 4; ++j)
        acc[4 + i][j] = __builtin_amdgcn_mfma_f32_16x16x32_bf16(af[4 + i], bf[j], acc[4 + i][j], 0, 0, 0);
    __builtin_amdgcn_s_setprio(0);
    if (st)  // steady state: newest tile's 4 loads stay in flight; the wait
             // retires tile t+1's 4 -> its data is ready for next iteration.
      asm volatile("s_waitcnt vmcnt(4)" ::: "memory");
    else     // tail: drain remaining loads (tile NT-1).
      asm volatile("s_waitcnt vmcnt(0)" ::: "memory");
    __builtin_amdgcn_s_barrier();

    b = (b == 2) ? 0 : b + 1;
  }

  // ---- epilogue: bias + store. C/D: col = lane&15, row = (lane>>4)*4 + r ----
  float bv[4];
  #pragma unroll
  for (int j = 0; j < 4; ++j)
    bv[j] = bias[bn * BN + wn * 64 + j * 16 + lr];
  #pragma unroll
  for (int i = 0; i < 8; ++i) {
    #pragma unroll
    for (int r = 0; r < 4; ++r) {
      int m = bm * BM + wm * 128 + i * 16 + lg * 4 + r;
      float* crow = C + (size_t)m * GN + bn * BN + wn * 64 + lr;
      #pragma unroll
      for (int j = 0; j < 4; ++j)
        crow[j * 16] = acc[i][j][r] + bv[j];
    }
  }
#undef STAGE_A
#undef STAGE_B
}

extern "C" void kernel_launch(void* const* d_in, const int* in_sizes, int n_in,
                              void* d_out, int out_size, void* d_ws, size_t ws_size,
                              hipStream_t stream) {
  const float* x    = (const float*)d_in[0];
  const float* w    = (const float*)d_in[1];
  const float* bias = (const float*)d_in[2];
  float* out = (float*)d_out;

  unsigned short* xbf = (unsigned short*)d_ws;
  unsigned short* wbf = xbf + (size_t)GM * GK;

  const int n8x = (GM * GK) / 8;            // 2M
  const int n8t = n8x + (GN * GK) / 8;      // 6M
  cvt_both<<<2048, 256, 0, stream>>>((const float4*)x, (const float4*)w,
                                     (uint4*)xbf, (uint4*)wbf, n8x, n8t);

  const int nwg = (GM / BM) * (GN / BN);    // 512
  gemm_bt_bias<<<nwg, 512, 0, stream>>>(xbf, wbf, bias, out);
}

// Round 5
// 533.602 us; speedup vs baseline: 1.0987x; 1.0216x over previous
//
#include <hip/hip_runtime.h>
#include <hip/hip_bf16.h>

// BanditLayer inference: out[M,N] = x[M,K] . w[N,K]^T + bias[N], fp32 I/O.
// Round 4 (resubmit): round-3 skeleton (256x256, BK=32, 3-deep pipeline,
// counted vmcnt) with a QUARTER-WAVE-correct LDS swizzle:
// phys_slot = lg ^ ((row>>1)&3). LDS b128 reads are processed as 16-lane
// quarters (lg constant within a quarter), so the XOR term must vary with
// lr -> spreads 16 lanes over all 8 slot classes (2/class = conflict-free).
// Round 3's (row&3) only hit 4 classes per quarter -> 4-way conflict
// (measured 4 cy/read, unchanged from unswizzled). Plus one-shot cvt kernel.

typedef __bf16 bf16x8 __attribute__((ext_vector_type(8)));
typedef float f32x4 __attribute__((ext_vector_type(4)));

#define GM 4096
#define GK 4096
#define GN 8192
#define BM 256
#define BN 256
#define BK 32
#define NT (GK / BK)   // 128 K-tiles

__device__ __forceinline__ unsigned f2bf_rne(float f) {
  union { float f; unsigned u; } v; v.f = f;
  unsigned r = 0x7FFFu + ((v.u >> 16) & 1u);
  return (v.u + r) >> 16;
}

// One-shot: thread i produces uint4 output i (8 bf16), exact grid, no loop.
__global__ void cvt_both(const float4* __restrict__ x4, const float4* __restrict__ w4,
                         uint4* __restrict__ xo4, uint4* __restrict__ wo4,
                         int n8x, int n8t) {
  int i = blockIdx.x * blockDim.x + threadIdx.x;
  if (i >= n8t) return;
  const float4* s; uint4* d; int j;
  if (i < n8x) { s = x4; d = xo4; j = i; }
  else         { s = w4; d = wo4; j = i - n8x; }
  float4 a = s[2 * j];
  float4 b = s[2 * j + 1];
  uint4 o;
  o.x = f2bf_rne(a.x) | (f2bf_rne(a.y) << 16);
  o.y = f2bf_rne(a.z) | (f2bf_rne(a.w) << 16);
  o.z = f2bf_rne(b.x) | (f2bf_rne(b.y) << 16);
  o.w = f2bf_rne(b.z) | (f2bf_rne(b.w) << 16);
  d[j] = o;
}

__device__ __forceinline__ void gload_lds16(const void* g, void* l) {
  __builtin_amdgcn_global_load_lds(
      (const __attribute__((address_space(1))) unsigned int*)g,
      (__attribute__((address_space(3))) unsigned int*)l, 16, 0, 0);
}

// LDS tile: [256 rows][32 k] bf16, rows = 64B = 4 slots of 16B.
// Swizzle: phys_slot = logical_slot ^ ((row>>1) & 3). Staging writes the
// physical layout linearly (global_load_lds dest = uniform base + lane*16),
// so the global SOURCE column is pre-swizzled with the same XOR (involution);
// ds_read applies it on the read side.

__launch_bounds__(512, 2)
__global__ void gemm_bt_bias(const unsigned short* __restrict__ A,  // GM x GK bf16
                             const unsigned short* __restrict__ B,  // GN x GK bf16
                             const float* __restrict__ bias,
                             float* __restrict__ C) {
  __shared__ __align__(1024) unsigned short As[3][BM * BK];  // 48 KB
  __shared__ __align__(1024) unsigned short Bs[3][BN * BK];  // 48 KB

  // XCD-aware bijective swizzle (512 wgs, %8==0).
  const int nwg = (GM / BM) * (GN / BN);   // 512
  int bid = blockIdx.x;
  int swz = (bid & 7) * (nwg >> 3) + (bid >> 3);
  const int bm = swz & 15;    // 16 tiles along M
  const int bn = swz >> 4;    // 32 tiles along N

  const int tid  = threadIdx.x;   // 0..511
  const int lane = tid & 63;
  const int wave = tid >> 6;      // 0..7
  const int wm = wave >> 2;       // 0..1  (M half: 128 rows)
  const int wn = wave & 3;        // 0..3  (N quarter: 64 cols)
  const int lr = lane & 15;
  const int lg = lane >> 4;       // 0..3

  // ---- staging: 1024 chunks of 16B per operand tile; thread covers c0=tid,
  // c1=tid+512. Pre-swizzled global source column: logical = phys ^ ((row>>1)&3).
  const int c0 = tid,       r0 = c0 >> 2, s0 = (c0 & 3) ^ ((c0 >> 3) & 3);
  const int c1 = tid + 512, r1 = c1 >> 2, s1 = (c1 & 3) ^ ((c1 >> 3) & 3);
  const unsigned short* aG0 = A + (size_t)(bm * BM + r0) * GK + s0 * 8;
  const unsigned short* aG1 = A + (size_t)(bm * BM + r1) * GK + s1 * 8;
  const unsigned short* bG0 = B + (size_t)(bn * BN + r0) * GK + s0 * 8;
  const unsigned short* bG1 = B + (size_t)(bn * BN + r1) * GK + s1 * 8;
  // LDS dest element offsets (wave-uniform base; HW adds lane*16B).
  const int d0 = (wave * 64) * 8;
  const int d1 = (512 + wave * 64) * 8;

#define STAGE_A(buf, kt) do { \
    gload_lds16(aG0 + (size_t)(kt) * BK, &As[buf][d0]); \
    gload_lds16(aG1 + (size_t)(kt) * BK, &As[buf][d1]); \
  } while (0)
#define STAGE_B(buf, kt) do { \
    gload_lds16(bG0 + (size_t)(kt) * BK, &Bs[buf][d0]); \
    gload_lds16(bG1 + (size_t)(kt) * BK, &Bs[buf][d1]); \
  } while (0)

  // ---- fragment read byte-offsets within one buffer ----
  // Frag i: row = base + lr (base multiple of 16), logical slot = lg,
  // phys = lg ^ ((lr>>1)&3)  [(base>>1)&3 == 0]. Row stride 64B.
  const int phys = lg ^ ((lr >> 1) & 3);
  const int aOff = (wm * 128 + lr) * 64 + phys * 16;   // + i*1024
  const int bOff = (wn * 64 + lr) * 64 + phys * 16;    // + j*1024

  f32x4 acc[8][4];
  #pragma unroll
  for (int i = 0; i < 8; ++i)
    #pragma unroll
    for (int j = 0; j < 4; ++j)
      acc[i][j] = (f32x4){0.f, 0.f, 0.f, 0.f};

  // ---- prologue: stage tiles 0 (buf0) and 1 (buf1) ----
  STAGE_A(0, 0); STAGE_B(0, 0);
  STAGE_A(1, 1); STAGE_B(1, 1);
  asm volatile("s_waitcnt vmcnt(4)" ::: "memory");   // tile 0 landed
  __builtin_amdgcn_s_barrier();

  int b = 0;
  for (int t = 0; t < NT; ++t) {
    const bool st = (t + 2) < NT;
    const int s = (b == 0) ? 2 : (b - 1);            // (b+2)%3: buffer for t+2
    const char* aB = (const char*)&As[b][0];
    const char* bB = (const char*)&Bs[b][0];

    bf16x8 af[8], bf[4];

    // ---- P1: read af[0..3], bf[0..3]; stage A(t+2); MFMA (m0-3 x n0-3) ----
    #pragma unroll
    for (int i = 0; i < 4; ++i)
      af[i] = *(const bf16x8*)(aB + aOff + i * 1024);
    #pragma unroll
    for (int j = 0; j < 4; ++j)
      bf[j] = *(const bf16x8*)(bB + bOff + j * 1024);
    if (st) STAGE_A(s, t + 2);
    __builtin_amdgcn_s_barrier();
    asm volatile("s_waitcnt lgkmcnt(0)" ::: "memory");
    __builtin_amdgcn_s_setprio(1);
    #pragma unroll
    for (int i = 0; i < 4; ++i)
      #pragma unroll
      for (int j = 0; j < 4; ++j)
        acc[i][j] = __builtin_amdgcn_mfma_f32_16x16x32_bf16(af[i], bf[j], acc[i][j], 0, 0, 0);
    __builtin_amdgcn_s_setprio(0);
    __builtin_amdgcn_s_barrier();

    // ---- P2: read af[4..7]; stage B(t+2); MFMA (m4-7 x n0-3); counted vmcnt ----
    #pragma unroll
    for (int i = 0; i < 4; ++i)
      af[4 + i] = *(const bf16x8*)(aB + aOff + (4 + i) * 1024);
    if (st) STAGE_B(s, t + 2);
    __builtin_amdgcn_s_barrier();
    asm volatile("s_waitcnt lgkmcnt(0)" ::: "memory");
    __builtin_amdgcn_s_setprio(1);
    #pragma unroll
    for (int i = 0; i < 4; ++i)
      #pragma unroll
      for (int j = 0; j < 4; ++j)
        acc[4 + i][j] = __builtin_amdgcn_mfma_f32_16x16x32_bf16(af[4 + i], bf[j], acc[4 + i][j], 0, 0, 0);
    __builtin_amdgcn_s_setprio(0);
    if (st)  // steady state: newest tile's 4 loads stay in flight; the wait
             // retires tile t+1's 4 -> its data is ready for next iteration.
      asm volatile("s_waitcnt vmcnt(4)" ::: "memory");
    else     // tail: drain remaining loads (tile NT-1).
      asm volatile("s_waitcnt vmcnt(0)" ::: "memory");
    __builtin_amdgcn_s_barrier();

    b = (b == 2) ? 0 : b + 1;
  }

  // ---- epilogue: bias + store. C/D: col = lane&15, row = (lane>>4)*4 + r ----
  float bv[4];
  #pragma unroll
  for (int j = 0; j < 4; ++j)
    bv[j] = bias[bn * BN + wn * 64 + j * 16 + lr];
  #pragma unroll
  for (int i = 0; i < 8; ++i) {
    #pragma unroll
    for (int r = 0; r < 4; ++r) {
      int m = bm * BM + wm * 128 + i * 16 + lg * 4 + r;
      float* crow = C + (size_t)m * GN + bn * BN + wn * 64 + lr;
      #pragma unroll
      for (int j = 0; j < 4; ++j)
        crow[j * 16] = acc[i][j][r] + bv[j];
    }
  }
#undef STAGE_A
#undef STAGE_B
}

extern "C" void kernel_launch(void* const* d_in, const int* in_sizes, int n_in,
                              void* d_out, int out_size, void* d_ws, size_t ws_size,
                              hipStream_t stream) {
  const float* x    = (const float*)d_in[0];
  const float* w    = (const float*)d_in[1];
  const float* bias = (const float*)d_in[2];
  float* out = (float*)d_out;

  unsigned short* xbf = (unsigned short*)d_ws;
  unsigned short* wbf = xbf + (size_t)GM * GK;

  const int n8x = (GM * GK) / 8;            // 2M uint4 outputs for x
  const int n8t = n8x + (GN * GK) / 8;      // 6M total
  const int cvt_blocks = (n8t + 255) / 256; // one-shot exact grid
  cvt_both<<<cvt_blocks, 256, 0, stream>>>((const float4*)x, (const float4*)w,
                                           (uint4*)xbf, (uint4*)wbf, n8x, n8t);

  const int nwg = (GM / BM) * (GN / BN);    // 512
  gemm_bt_bias<<<nwg, 512, 0, stream>>>(xbf, wbf, bias, out);
}